// Round 1
// baseline (1478.641 us; speedup 1.0000x reference)
//
#include <hip/hip_runtime.h>

// GCN: z1 = relu(Agg(x@W1)+b1); z2 = Agg(z1@W2)+b2; out = meanpool(z2)@Wfc + bfc
// Agg(h)[d] = dinv[d]^2 * h[d] + sum_{e: s->d} dinv[s]*w[e]*dinv[d] * h[s]
// deg[d] = 1 + sum_{e: s->d} w[e]   (self-loop weight 1)

constexpr int FDIM = 128;

// ---------------- init ----------------
__global__ __launch_bounds__(256) void k_init(float* deg, int* cnt, float* psum,
                                              int* gcnt, int NN, int PS, int G) {
    int i = blockIdx.x * 256 + threadIdx.x;
    if (i < NN) { deg[i] = 1.0f; cnt[i] = 0; }
    if (i < PS) psum[i] = 0.0f;
    if (i < G) gcnt[i] = 0;
}

// ---------------- degree + count histogram ----------------
__global__ __launch_bounds__(256) void k_degcnt(const int* __restrict__ dst,
                                                const float* __restrict__ ew,
                                                float* deg, int* cnt, int E) {
    int e = blockIdx.x * 256 + threadIdx.x;
    if (e < E) {
        int d = dst[e];
        atomicAdd(&deg[d], ew[e]);
        atomicAdd(&cnt[d], 1);
    }
}

__global__ __launch_bounds__(256) void k_dinv(float* deg, int NN) {
    int i = blockIdx.x * 256 + threadIdx.x;
    if (i < NN) deg[i] = rsqrtf(deg[i]);   // deg >= 1 always (self-loop)
}

// ---------------- exclusive scan of cnt -> rowptr (3-kernel, chunk=1024) ------
__global__ __launch_bounds__(256) void k_bsum(const int* __restrict__ cnt, int* bsum, int NN) {
    __shared__ int lds[256];
    int b = blockIdx.x, t = threadIdx.x;
    int base = b * 1024;
    int s = 0;
#pragma unroll
    for (int j = 0; j < 4; j++) {
        int i = base + j * 256 + t;
        if (i < NN) s += cnt[i];
    }
    lds[t] = s;
    __syncthreads();
    for (int off = 128; off > 0; off >>= 1) {
        if (t < off) lds[t] += lds[t + off];
        __syncthreads();
    }
    if (t == 0) bsum[b] = lds[0];
}

__global__ __launch_bounds__(256) void k_btops(const int* bsum, int* boff, int* rowptr,
                                               int NB, int NN) {
    __shared__ int lds[256];
    int t = threadIdx.x;
    if (t < NB) lds[t] = bsum[t];
    __syncthreads();
    if (t == 0) {
        int run = 0;
        for (int i = 0; i < NB; i++) { int v = lds[i]; boff[i] = run; run += v; }
        rowptr[NN] = run;   // == E
    }
}

__global__ __launch_bounds__(256) void k_scan(const int* __restrict__ cnt,
                                              const int* __restrict__ boff,
                                              int* rowptr, int* fillpos, int NN) {
    __shared__ int lds[2][256];
    int b = blockIdx.x, t = threadIdx.x;
    int base = b * 1024 + t * 4;
    int v[4]; int s = 0;
#pragma unroll
    for (int j = 0; j < 4; j++) { v[j] = (base + j < NN) ? cnt[base + j] : 0; s += v[j]; }
    lds[0][t] = s;
    __syncthreads();
    int cur = 0;
    for (int off = 1; off < 256; off <<= 1) {
        int val = lds[cur][t];
        if (t >= off) val += lds[cur][t - off];
        lds[cur ^ 1][t] = val;
        __syncthreads();
        cur ^= 1;
    }
    int excl = lds[cur][t] - s + boff[b];
#pragma unroll
    for (int j = 0; j < 4; j++) {
        if (base + j < NN) { rowptr[base + j] = excl; fillpos[base + j] = excl; }
        excl += v[j];
    }
}

// ---------------- CSR fill (src + precomputed edge norm) ----------------
__global__ __launch_bounds__(256) void k_fill(const int* __restrict__ src,
                                              const int* __restrict__ dst,
                                              const float* __restrict__ ew,
                                              const float* __restrict__ dinv,
                                              int* fillpos, int* csr_src, float* csr_nrm,
                                              int E) {
    int e = blockIdx.x * 256 + threadIdx.x;
    if (e < E) {
        int d = dst[e], s = src[e];
        int pos = atomicAdd(&fillpos[d], 1);
        csr_src[pos] = s;
        csr_nrm[pos] = dinv[s] * ew[e] * dinv[d];
    }
}

// ---------------- fp32 GEMM: H[N,128] = X[N,128] @ W[128,128] ----------------
// block: 256 threads, 64 rows; thread (ty=t>>4, tx=t&15) owns rows ty+16i (i<4),
// cols tx*8..tx*8+7. W k-tile + transposed x-tile staged in LDS.
__global__ __launch_bounds__(256) void k_gemm(const float* __restrict__ X,
                                              const float* __restrict__ W,
                                              float* __restrict__ H, int N) {
    __shared__ float xs[16][65];    // xs[k][r], padded
    __shared__ float wsh[16][128];  // wsh[k][c]
    int t = threadIdx.x;
    int tx = t & 15, ty = t >> 4;
    int r0 = blockIdx.x * 64;
    float acc[4][8];
#pragma unroll
    for (int i = 0; i < 4; i++)
#pragma unroll
        for (int j = 0; j < 8; j++) acc[i][j] = 0.0f;

    int lr = t >> 2;            // 0..63  x-load row
    int lk = (t & 3) * 4;       // k sub-offset
    int wr = t >> 4;            // 0..15  W-load row
    int wc = (t & 15) * 8;      // W-load col

    for (int k0 = 0; k0 < 128; k0 += 16) {
        float4 xv = make_float4(0.f, 0.f, 0.f, 0.f);
        int gr = r0 + lr;
        if (gr < N) xv = *(const float4*)(X + (size_t)gr * FDIM + k0 + lk);
        xs[lk + 0][lr] = xv.x; xs[lk + 1][lr] = xv.y;
        xs[lk + 2][lr] = xv.z; xs[lk + 3][lr] = xv.w;
        float4 wv0 = *(const float4*)(W + (size_t)(k0 + wr) * FDIM + wc);
        float4 wv1 = *(const float4*)(W + (size_t)(k0 + wr) * FDIM + wc + 4);
        *(float4*)&wsh[wr][wc] = wv0;
        *(float4*)&wsh[wr][wc + 4] = wv1;
        __syncthreads();
#pragma unroll
        for (int k = 0; k < 16; k++) {
            float xr[4];
#pragma unroll
            for (int i = 0; i < 4; i++) xr[i] = xs[k][ty + 16 * i];
            float4 w0 = *(float4*)&wsh[k][tx * 8];
            float4 w1 = *(float4*)&wsh[k][tx * 8 + 4];
            float wv[8] = {w0.x, w0.y, w0.z, w0.w, w1.x, w1.y, w1.z, w1.w};
#pragma unroll
            for (int i = 0; i < 4; i++)
#pragma unroll
                for (int j = 0; j < 8; j++)
                    acc[i][j] = fmaf(xr[i], wv[j], acc[i][j]);
        }
        __syncthreads();
    }
#pragma unroll
    for (int i = 0; i < 4; i++) {
        int r = r0 + ty + 16 * i;
        if (r < N) {
            float4 o0 = make_float4(acc[i][0], acc[i][1], acc[i][2], acc[i][3]);
            float4 o1 = make_float4(acc[i][4], acc[i][5], acc[i][6], acc[i][7]);
            *(float4*)(H + (size_t)r * FDIM + tx * 8) = o0;
            *(float4*)(H + (size_t)r * FDIM + tx * 8 + 4) = o1;
        }
    }
}

// ---------------- gather aggregation (1 wave per node, float2 per lane) -------
// RELU: apply relu after bias.  POOL: atomicAdd into psum[g] instead of storing Z.
template <int RELU, int POOL>
__global__ __launch_bounds__(256) void k_agg(const float* __restrict__ H,
                                             const int* __restrict__ rowptr,
                                             const int* __restrict__ csr_src,
                                             const float* __restrict__ csr_nrm,
                                             const float* __restrict__ dinv,
                                             const float* __restrict__ bias,
                                             float* __restrict__ Z,
                                             const int* __restrict__ batch,
                                             float* psum, int* gcnt, int NN) {
    int wave = threadIdx.x >> 6;
    int lane = threadIdx.x & 63;
    int n = blockIdx.x * 4 + wave;
    if (n >= NN) return;
    int f0 = lane * 2;
    float di = dinv[n];
    float sw = di * di;
    float2 hv = *(const float2*)(H + (size_t)n * FDIM + f0);
    float ax = sw * hv.x, ay = sw * hv.y;
    int rs = rowptr[n], re = rowptr[n + 1];
    for (int e = rs; e < re; ++e) {
        int s = csr_src[e];
        float w = csr_nrm[e];
        float2 v = *(const float2*)(H + (size_t)s * FDIM + f0);
        ax = fmaf(w, v.x, ax);
        ay = fmaf(w, v.y, ay);
    }
    ax += bias[f0]; ay += bias[f0 + 1];
    if (RELU) { ax = fmaxf(ax, 0.0f); ay = fmaxf(ay, 0.0f); }
    if (POOL) {
        int g = batch[n];
        atomicAdd(&psum[g * FDIM + f0], ax);
        atomicAdd(&psum[g * FDIM + f0 + 1], ay);
        if (lane == 0) atomicAdd(&gcnt[g], 1);
    } else {
        *(float2*)(Z + (size_t)n * FDIM + f0) = make_float2(ax, ay);
    }
}

// ---------------- mean + final FC: out[g] = (psum[g]/cnt) @ Wfc + bfc ---------
__global__ __launch_bounds__(128) void k_fc(const float* __restrict__ psum,
                                            const int* __restrict__ gcnt,
                                            const float* __restrict__ Wfc,
                                            const float* __restrict__ bfc,
                                            float* __restrict__ out) {
    __shared__ float p[FDIM];
    int g = blockIdx.x, f = threadIdx.x;
    float c = (float)max(gcnt[g], 1);
    p[f] = psum[g * FDIM + f] / c;
    __syncthreads();
    float acc = bfc[f];
#pragma unroll 8
    for (int k = 0; k < FDIM; k++) acc = fmaf(p[k], Wfc[k * FDIM + f], acc);
    out[g * FDIM + f] = acc;
}

extern "C" void kernel_launch(void* const* d_in, const int* in_sizes, int n_in,
                              void* d_out, int out_size, void* d_ws, size_t ws_size,
                              hipStream_t stream) {
    const float* x    = (const float*)d_in[0];
    const int*   ei   = (const int*)d_in[1];
    const float* ew   = (const float*)d_in[2];
    const int*   batch= (const int*)d_in[3];
    const float* W1   = (const float*)d_in[4];
    const float* b1   = (const float*)d_in[5];
    const float* W2   = (const float*)d_in[6];
    const float* b2   = (const float*)d_in[7];
    const float* Wfc  = (const float*)d_in[8];
    const float* bfc  = (const float*)d_in[9];
    float* out = (float*)d_out;

    int E  = in_sizes[2];       // 1,600,000
    int NN = in_sizes[3];       // 100,000
    int G  = out_size / FDIM;   // 64

    const int* src = ei;
    const int* dst = ei + E;

    char* ws = (char*)d_ws;
    size_t off = 0;
    auto alloc = [&](size_t bytes) -> void* {
        void* p = ws + off;
        off = (off + bytes + 255) & ~(size_t)255;
        return p;
    };
    float* deg     = (float*)alloc((size_t)NN * 4);       // becomes dinv in-place
    int*   cnt     = (int*)alloc((size_t)NN * 4);
    int*   rowptr  = (int*)alloc((size_t)(NN + 1) * 4);
    int*   fillpos = (int*)alloc((size_t)NN * 4);
    int*   bsum    = (int*)alloc(256 * 4);
    int*   boff    = (int*)alloc(256 * 4);
    int*   csr_src = (int*)alloc((size_t)E * 4);
    float* csr_nrm = (float*)alloc((size_t)E * 4);
    float* psum    = (float*)alloc((size_t)G * FDIM * 4);
    int*   gcnt    = (int*)alloc((size_t)G * 4);
    float* Bh      = (float*)alloc((size_t)NN * FDIM * 4);
    float* Bz      = (float*)alloc((size_t)NN * FDIM * 4);
    (void)ws_size; (void)n_in;

    int nbN = (NN + 255) / 256;
    int nbE = (E + 255) / 256;
    int NB  = (NN + 1023) / 1024;   // 98

    k_init<<<nbN, 256, 0, stream>>>(deg, cnt, psum, gcnt, NN, G * FDIM, G);
    k_degcnt<<<nbE, 256, 0, stream>>>(dst, ew, deg, cnt, E);
    k_dinv<<<nbN, 256, 0, stream>>>(deg, NN);
    k_bsum<<<NB, 256, 0, stream>>>(cnt, bsum, NN);
    k_btops<<<1, 256, 0, stream>>>(bsum, boff, rowptr, NB, NN);
    k_scan<<<NB, 256, 0, stream>>>(cnt, boff, rowptr, fillpos, NN);
    k_fill<<<nbE, 256, 0, stream>>>(src, dst, ew, deg, fillpos, csr_src, csr_nrm, E);

    int nbG = (NN + 63) / 64;
    int nbA = (NN + 3) / 4;
    // layer 1: h1 = x@W1 ; z1 = relu(Agg(h1)+b1)
    k_gemm<<<nbG, 256, 0, stream>>>(x, W1, Bh, NN);
    k_agg<1, 0><<<nbA, 256, 0, stream>>>(Bh, rowptr, csr_src, csr_nrm, deg, b1,
                                         Bz, batch, psum, gcnt, NN);
    // layer 2: h2 = z1@W2 ; z2 = Agg(h2)+b2, fused mean-pool accumulation
    k_gemm<<<nbG, 256, 0, stream>>>(Bz, W2, Bh, NN);
    k_agg<0, 1><<<nbA, 256, 0, stream>>>(Bh, rowptr, csr_src, csr_nrm, deg, b2,
                                         nullptr, batch, psum, gcnt, NN);
    // out = (psum/cnt) @ Wfc + bfc
    k_fc<<<G, 128, 0, stream>>>(psum, gcnt, Wfc, bfc, out);
}

// Round 2
// 657.670 us; speedup vs baseline: 2.2483x; 2.2483x over previous
//
#include <hip/hip_runtime.h>

// GCN: z1 = relu(Agg(x@W1)+b1); z2 = Agg(z1@W2)+b2; out = meanpool(z2)@Wfc + bfc
// Agg(h)[d] = dinv[d]^2 * h[d] + sum_{e: s->d} dinv[s]*w[e]*dinv[d] * h[s]
// deg[d] = 1 + sum_{e: s->d} w[e]   (self-loop weight 1)

constexpr int FDIM = 128;

// ---------------- init ----------------
__global__ __launch_bounds__(256) void k_init(float* deg, int* cnt, float* psum,
                                              int* gcnt, int NN, int PS, int G) {
    int i = blockIdx.x * 256 + threadIdx.x;
    if (i < NN) { deg[i] = 1.0f; cnt[i] = 0; }
    if (i < PS) psum[i] = 0.0f;
    if (i < G) gcnt[i] = 0;
}

// ---------------- degree + count histogram ----------------
__global__ __launch_bounds__(256) void k_degcnt(const int* __restrict__ dst,
                                                const float* __restrict__ ew,
                                                float* deg, int* cnt, int E) {
    int e = blockIdx.x * 256 + threadIdx.x;
    if (e < E) {
        int d = dst[e];
        atomicAdd(&deg[d], ew[e]);
        atomicAdd(&cnt[d], 1);
    }
}

__global__ __launch_bounds__(256) void k_dinv(float* deg, int NN) {
    int i = blockIdx.x * 256 + threadIdx.x;
    if (i < NN) deg[i] = rsqrtf(deg[i]);   // deg >= 1 always (self-loop)
}

// ---------------- exclusive scan of cnt -> rowptr (3-kernel, chunk=1024) ------
__global__ __launch_bounds__(256) void k_bsum(const int* __restrict__ cnt, int* bsum, int NN) {
    __shared__ int lds[256];
    int b = blockIdx.x, t = threadIdx.x;
    int base = b * 1024;
    int s = 0;
#pragma unroll
    for (int j = 0; j < 4; j++) {
        int i = base + j * 256 + t;
        if (i < NN) s += cnt[i];
    }
    lds[t] = s;
    __syncthreads();
    for (int off = 128; off > 0; off >>= 1) {
        if (t < off) lds[t] += lds[t + off];
        __syncthreads();
    }
    if (t == 0) bsum[b] = lds[0];
}

__global__ __launch_bounds__(256) void k_btops(const int* bsum, int* boff, int* rowptr,
                                               int NB, int NN) {
    __shared__ int lds[256];
    int t = threadIdx.x;
    if (t < NB) lds[t] = bsum[t];
    __syncthreads();
    if (t == 0) {
        int run = 0;
        for (int i = 0; i < NB; i++) { int v = lds[i]; boff[i] = run; run += v; }
        rowptr[NN] = run;   // == E
    }
}

__global__ __launch_bounds__(256) void k_scan(const int* __restrict__ cnt,
                                              const int* __restrict__ boff,
                                              int* rowptr, int* fillpos, int NN) {
    __shared__ int lds[2][256];
    int b = blockIdx.x, t = threadIdx.x;
    int base = b * 1024 + t * 4;
    int v[4]; int s = 0;
#pragma unroll
    for (int j = 0; j < 4; j++) { v[j] = (base + j < NN) ? cnt[base + j] : 0; s += v[j]; }
    lds[0][t] = s;
    __syncthreads();
    int cur = 0;
    for (int off = 1; off < 256; off <<= 1) {
        int val = lds[cur][t];
        if (t >= off) val += lds[cur][t - off];
        lds[cur ^ 1][t] = val;
        __syncthreads();
        cur ^= 1;
    }
    int excl = lds[cur][t] - s + boff[b];
#pragma unroll
    for (int j = 0; j < 4; j++) {
        if (base + j < NN) { rowptr[base + j] = excl; fillpos[base + j] = excl; }
        excl += v[j];
    }
}

// ---------------- CSR fill (src + precomputed edge norm) ----------------
__global__ __launch_bounds__(256) void k_fill(const int* __restrict__ src,
                                              const int* __restrict__ dst,
                                              const float* __restrict__ ew,
                                              const float* __restrict__ dinv,
                                              int* fillpos, int* csr_src, float* csr_nrm,
                                              int E) {
    int e = blockIdx.x * 256 + threadIdx.x;
    if (e < E) {
        int d = dst[e], s = src[e];
        int pos = atomicAdd(&fillpos[d], 1);
        csr_src[pos] = s;
        csr_nrm[pos] = dinv[s] * ew[e] * dinv[d];
    }
}

// ---------------- fp32 GEMM: H[N,128] = X[N,128] @ W[128,128] ----------------
__global__ __launch_bounds__(256) void k_gemm(const float* __restrict__ X,
                                              const float* __restrict__ W,
                                              float* __restrict__ H, int N) {
    __shared__ float xs[16][65];    // xs[k][r], padded
    __shared__ float wsh[16][128];  // wsh[k][c]
    int t = threadIdx.x;
    int tx = t & 15, ty = t >> 4;
    int r0 = blockIdx.x * 64;
    float acc[4][8];
#pragma unroll
    for (int i = 0; i < 4; i++)
#pragma unroll
        for (int j = 0; j < 8; j++) acc[i][j] = 0.0f;

    int lr = t >> 2;            // 0..63  x-load row
    int lk = (t & 3) * 4;       // k sub-offset
    int wr = t >> 4;            // 0..15  W-load row
    int wc = (t & 15) * 8;      // W-load col

    for (int k0 = 0; k0 < 128; k0 += 16) {
        float4 xv = make_float4(0.f, 0.f, 0.f, 0.f);
        int gr = r0 + lr;
        if (gr < N) xv = *(const float4*)(X + (size_t)gr * FDIM + k0 + lk);
        xs[lk + 0][lr] = xv.x; xs[lk + 1][lr] = xv.y;
        xs[lk + 2][lr] = xv.z; xs[lk + 3][lr] = xv.w;
        float4 wv0 = *(const float4*)(W + (size_t)(k0 + wr) * FDIM + wc);
        float4 wv1 = *(const float4*)(W + (size_t)(k0 + wr) * FDIM + wc + 4);
        *(float4*)&wsh[wr][wc] = wv0;
        *(float4*)&wsh[wr][wc + 4] = wv1;
        __syncthreads();
#pragma unroll
        for (int k = 0; k < 16; k++) {
            float xr[4];
#pragma unroll
            for (int i = 0; i < 4; i++) xr[i] = xs[k][ty + 16 * i];
            float4 w0 = *(float4*)&wsh[k][tx * 8];
            float4 w1 = *(float4*)&wsh[k][tx * 8 + 4];
            float wv[8] = {w0.x, w0.y, w0.z, w0.w, w1.x, w1.y, w1.z, w1.w};
#pragma unroll
            for (int i = 0; i < 4; i++)
#pragma unroll
                for (int j = 0; j < 8; j++)
                    acc[i][j] = fmaf(xr[i], wv[j], acc[i][j]);
        }
        __syncthreads();
    }
#pragma unroll
    for (int i = 0; i < 4; i++) {
        int r = r0 + ty + 16 * i;
        if (r < N) {
            float4 o0 = make_float4(acc[i][0], acc[i][1], acc[i][2], acc[i][3]);
            float4 o1 = make_float4(acc[i][4], acc[i][5], acc[i][6], acc[i][7]);
            *(float4*)(H + (size_t)r * FDIM + tx * 8) = o0;
            *(float4*)(H + (size_t)r * FDIM + tx * 8 + 4) = o1;
        }
    }
}

// ---------------- gather aggregation v2 ----------------
// 2 nodes per wave (32 lanes x float4 each), 8-wide batched edge gather for MLP.
// RELU: relu after bias.  POOL: LDS-pre-reduced mean-pool accumulation.
template <int RELU, int POOL>
__global__ __launch_bounds__(256) void k_agg(const float* __restrict__ H,
                                             const int* __restrict__ rowptr,
                                             const int* __restrict__ csr_src,
                                             const float* __restrict__ csr_nrm,
                                             const float* __restrict__ dinv,
                                             const float* __restrict__ bias,
                                             float* __restrict__ Z,
                                             const int* __restrict__ batch,
                                             float* psum, int* gcnt, int NN) {
    __shared__ float pool[FDIM];
    __shared__ int pcnt;
    int t = threadIdx.x;
    int wave = t >> 6, lane = t & 63;
    int half = lane >> 5, li = lane & 31;
    int n = blockIdx.x * 8 + wave * 2 + half;
    int gmin = 0;
    if (POOL) {
        if (t < FDIM) pool[t] = 0.0f;
        if (t == 0) pcnt = 0;
        gmin = batch[blockIdx.x * 8];   // grid sized so this node exists
        __syncthreads();
    }
    if (n < NN) {
        int f0 = li * 4;
        float di = dinv[n];
        float sw = di * di;
        float4 hv = *(const float4*)(H + (size_t)n * FDIM + f0);
        float4 acc;
        acc.x = sw * hv.x; acc.y = sw * hv.y; acc.z = sw * hv.z; acc.w = sw * hv.w;
        int rs = rowptr[n], re = rowptr[n + 1];
        for (int e = rs; e < re; e += 8) {
            int s[8]; float w[8];
#pragma unroll
            for (int j = 0; j < 8; j++) {
                int idx = e + j;
                int cidx = min(idx, re - 1);          // always-valid address
                s[j] = csr_src[cidx];
                w[j] = (idx < re) ? csr_nrm[cidx] : 0.0f;
            }
            float4 v[8];
#pragma unroll
            for (int j = 0; j < 8; j++)
                v[j] = *(const float4*)(H + (size_t)s[j] * FDIM + f0);
#pragma unroll
            for (int j = 0; j < 8; j++) {
                acc.x = fmaf(w[j], v[j].x, acc.x);
                acc.y = fmaf(w[j], v[j].y, acc.y);
                acc.z = fmaf(w[j], v[j].z, acc.z);
                acc.w = fmaf(w[j], v[j].w, acc.w);
            }
        }
        acc.x += bias[f0]; acc.y += bias[f0 + 1];
        acc.z += bias[f0 + 2]; acc.w += bias[f0 + 3];
        if (RELU) {
            acc.x = fmaxf(acc.x, 0.0f); acc.y = fmaxf(acc.y, 0.0f);
            acc.z = fmaxf(acc.z, 0.0f); acc.w = fmaxf(acc.w, 0.0f);
        }
        if (POOL) {
            int g = batch[n];
            if (g == gmin) {
                atomicAdd(&pool[f0 + 0], acc.x);
                atomicAdd(&pool[f0 + 1], acc.y);
                atomicAdd(&pool[f0 + 2], acc.z);
                atomicAdd(&pool[f0 + 3], acc.w);
                if (li == 0) atomicAdd(&pcnt, 1);
            } else {
                atomicAdd(&psum[g * FDIM + f0 + 0], acc.x);
                atomicAdd(&psum[g * FDIM + f0 + 1], acc.y);
                atomicAdd(&psum[g * FDIM + f0 + 2], acc.z);
                atomicAdd(&psum[g * FDIM + f0 + 3], acc.w);
                if (li == 0) atomicAdd(&gcnt[g], 1);
            }
        } else {
            *(float4*)(Z + (size_t)n * FDIM + f0) = acc;
        }
    }
    if (POOL) {
        __syncthreads();
        if (t < FDIM) atomicAdd(&psum[gmin * FDIM + t], pool[t]);
        if (t == 0) atomicAdd(&gcnt[gmin], pcnt);
    }
}

// ---------------- mean + final FC: out[g] = (psum[g]/cnt) @ Wfc + bfc ---------
__global__ __launch_bounds__(128) void k_fc(const float* __restrict__ psum,
                                            const int* __restrict__ gcnt,
                                            const float* __restrict__ Wfc,
                                            const float* __restrict__ bfc,
                                            float* __restrict__ out) {
    __shared__ float p[FDIM];
    int g = blockIdx.x, f = threadIdx.x;
    float c = (float)max(gcnt[g], 1);
    p[f] = psum[g * FDIM + f] / c;
    __syncthreads();
    float acc = bfc[f];
#pragma unroll 8
    for (int k = 0; k < FDIM; k++) acc = fmaf(p[k], Wfc[k * FDIM + f], acc);
    out[g * FDIM + f] = acc;
}

extern "C" void kernel_launch(void* const* d_in, const int* in_sizes, int n_in,
                              void* d_out, int out_size, void* d_ws, size_t ws_size,
                              hipStream_t stream) {
    const float* x    = (const float*)d_in[0];
    const int*   ei   = (const int*)d_in[1];
    const float* ew   = (const float*)d_in[2];
    const int*   batch= (const int*)d_in[3];
    const float* W1   = (const float*)d_in[4];
    const float* b1   = (const float*)d_in[5];
    const float* W2   = (const float*)d_in[6];
    const float* b2   = (const float*)d_in[7];
    const float* Wfc  = (const float*)d_in[8];
    const float* bfc  = (const float*)d_in[9];
    float* out = (float*)d_out;

    int E  = in_sizes[2];       // 1,600,000
    int NN = in_sizes[3];       // 100,000
    int G  = out_size / FDIM;   // 64

    const int* src = ei;
    const int* dst = ei + E;

    char* ws = (char*)d_ws;
    size_t off = 0;
    auto alloc = [&](size_t bytes) -> void* {
        void* p = ws + off;
        off = (off + bytes + 255) & ~(size_t)255;
        return p;
    };
    float* deg     = (float*)alloc((size_t)NN * 4);       // becomes dinv in-place
    int*   cnt     = (int*)alloc((size_t)NN * 4);
    int*   rowptr  = (int*)alloc((size_t)(NN + 1) * 4);
    int*   fillpos = (int*)alloc((size_t)NN * 4);
    int*   bsum    = (int*)alloc(256 * 4);
    int*   boff    = (int*)alloc(256 * 4);
    int*   csr_src = (int*)alloc((size_t)E * 4);
    float* csr_nrm = (float*)alloc((size_t)E * 4);
    float* psum    = (float*)alloc((size_t)G * FDIM * 4);
    int*   gcnt    = (int*)alloc((size_t)G * 4);
    float* Bh      = (float*)alloc((size_t)NN * FDIM * 4);
    float* Bz      = (float*)alloc((size_t)NN * FDIM * 4);
    (void)ws_size; (void)n_in;

    int nbN = (NN + 255) / 256;
    int nbE = (E + 255) / 256;
    int NB  = (NN + 1023) / 1024;   // 98

    k_init<<<nbN, 256, 0, stream>>>(deg, cnt, psum, gcnt, NN, G * FDIM, G);
    k_degcnt<<<nbE, 256, 0, stream>>>(dst, ew, deg, cnt, E);
    k_dinv<<<nbN, 256, 0, stream>>>(deg, NN);
    k_bsum<<<NB, 256, 0, stream>>>(cnt, bsum, NN);
    k_btops<<<1, 256, 0, stream>>>(bsum, boff, rowptr, NB, NN);
    k_scan<<<NB, 256, 0, stream>>>(cnt, boff, rowptr, fillpos, NN);
    k_fill<<<nbE, 256, 0, stream>>>(src, dst, ew, deg, fillpos, csr_src, csr_nrm, E);

    int nbG = (NN + 63) / 64;
    int nbA = (NN + 7) / 8;
    // layer 1: h1 = x@W1 ; z1 = relu(Agg(h1)+b1)
    k_gemm<<<nbG, 256, 0, stream>>>(x, W1, Bh, NN);
    k_agg<1, 0><<<nbA, 256, 0, stream>>>(Bh, rowptr, csr_src, csr_nrm, deg, b1,
                                         Bz, batch, psum, gcnt, NN);
    // layer 2: h2 = z1@W2 ; z2 = Agg(h2)+b2, fused mean-pool accumulation
    k_gemm<<<nbG, 256, 0, stream>>>(Bz, W2, Bh, NN);
    k_agg<0, 1><<<nbA, 256, 0, stream>>>(Bh, rowptr, csr_src, csr_nrm, deg, b2,
                                         nullptr, batch, psum, gcnt, NN);
    // out = (psum/cnt) @ Wfc + bfc
    k_fc<<<G, 128, 0, stream>>>(psum, gcnt, Wfc, bfc, out);
}

// Round 3
// 533.918 us; speedup vs baseline: 2.7694x; 1.2318x over previous
//
#include <hip/hip_runtime.h>

// GCN: z1 = relu(Agg(x@W1)+b1); z2 = Agg(z1@W2)+b2; out = meanpool(z2)@Wfc + bfc
// Agg(h)[d] = dinv[d]^2 * h[d] + sum_{e: s->d} dinv[s]*w[e]*dinv[d] * h[s]
// Intermediates (h1, z1, h2) kept in bf16; accumulation fp32; MFMA GEMMs.

constexpr int FDIM = 128;

typedef __attribute__((ext_vector_type(8))) short short8v;
typedef __attribute__((ext_vector_type(4))) float f32x4;

__device__ __forceinline__ ushort f2bf(float f) {
    uint u = __float_as_uint(f);
    return (ushort)((u + 0x7fffu + ((u >> 16) & 1u)) >> 16);
}
__device__ __forceinline__ float bf2f_lo(uint d) { return __uint_as_float(d << 16); }
__device__ __forceinline__ float bf2f_hi(uint d) { return __uint_as_float(d & 0xffff0000u); }

// ---------------- init ----------------
__global__ __launch_bounds__(256) void k_init(float* deg, int* cnt, float* psum,
                                              int* gcnt, int NN, int PS, int G) {
    int i = blockIdx.x * 256 + threadIdx.x;
    if (i < NN) { deg[i] = 1.0f; cnt[i] = 0; }
    if (i < PS) psum[i] = 0.0f;
    if (i < G) gcnt[i] = 0;
}

// ---------------- degree + count histogram ----------------
__global__ __launch_bounds__(256) void k_degcnt(const int* __restrict__ dst,
                                                const float* __restrict__ ew,
                                                float* deg, int* cnt, int E) {
    int e = blockIdx.x * 256 + threadIdx.x;
    if (e < E) {
        int d = dst[e];
        atomicAdd(&deg[d], ew[e]);
        atomicAdd(&cnt[d], 1);
    }
}

__global__ __launch_bounds__(256) void k_dinv(float* deg, int NN) {
    int i = blockIdx.x * 256 + threadIdx.x;
    if (i < NN) deg[i] = rsqrtf(deg[i]);   // deg >= 1 always (self-loop)
}

// ---------------- exclusive scan of cnt -> rowptr (3-kernel, chunk=1024) ------
__global__ __launch_bounds__(256) void k_bsum(const int* __restrict__ cnt, int* bsum, int NN) {
    __shared__ int lds[256];
    int b = blockIdx.x, t = threadIdx.x;
    int base = b * 1024;
    int s = 0;
#pragma unroll
    for (int j = 0; j < 4; j++) {
        int i = base + j * 256 + t;
        if (i < NN) s += cnt[i];
    }
    lds[t] = s;
    __syncthreads();
    for (int off = 128; off > 0; off >>= 1) {
        if (t < off) lds[t] += lds[t + off];
        __syncthreads();
    }
    if (t == 0) bsum[b] = lds[0];
}

__global__ __launch_bounds__(256) void k_btops(const int* bsum, int* boff, int* rowptr,
                                               int NB, int NN) {
    __shared__ int lds[256];
    int t = threadIdx.x;
    if (t < NB) lds[t] = bsum[t];
    __syncthreads();
    if (t == 0) {
        int run = 0;
        for (int i = 0; i < NB; i++) { int v = lds[i]; boff[i] = run; run += v; }
        rowptr[NN] = run;   // == E
    }
}

__global__ __launch_bounds__(256) void k_scan(const int* __restrict__ cnt,
                                              const int* __restrict__ boff,
                                              int* rowptr, int* fillpos, int NN) {
    __shared__ int lds[2][256];
    int b = blockIdx.x, t = threadIdx.x;
    int base = b * 1024 + t * 4;
    int v[4]; int s = 0;
#pragma unroll
    for (int j = 0; j < 4; j++) { v[j] = (base + j < NN) ? cnt[base + j] : 0; s += v[j]; }
    lds[0][t] = s;
    __syncthreads();
    int cur = 0;
    for (int off = 1; off < 256; off <<= 1) {
        int val = lds[cur][t];
        if (t >= off) val += lds[cur][t - off];
        lds[cur ^ 1][t] = val;
        __syncthreads();
        cur ^= 1;
    }
    int excl = lds[cur][t] - s + boff[b];
#pragma unroll
    for (int j = 0; j < 4; j++) {
        if (base + j < NN) { rowptr[base + j] = excl; fillpos[base + j] = excl; }
        excl += v[j];
    }
}

// ---------------- CSR fill (src + precomputed edge norm) ----------------
__global__ __launch_bounds__(256) void k_fill(const int* __restrict__ src,
                                              const int* __restrict__ dst,
                                              const float* __restrict__ ew,
                                              const float* __restrict__ dinv,
                                              int* fillpos, int* csr_src, float* csr_nrm,
                                              int E) {
    int e = blockIdx.x * 256 + threadIdx.x;
    if (e < E) {
        int d = dst[e], s = src[e];
        int pos = atomicAdd(&fillpos[d], 1);
        csr_src[pos] = s;
        csr_nrm[pos] = dinv[s] * ew[e] * dinv[d];
    }
}

// ---------------- fp32 -> bf16 cast (8 elems / thread) ----------------
__global__ __launch_bounds__(256) void k_castx(const float* __restrict__ x,
                                               ushort* __restrict__ Xb, int total8) {
    int i = blockIdx.x * 256 + threadIdx.x;
    if (i < total8) {
        float4 a = *(const float4*)(x + (size_t)i * 8);
        float4 b = *(const float4*)(x + (size_t)i * 8 + 4);
        uint4 o;
        o.x = (uint)f2bf(a.x) | ((uint)f2bf(a.y) << 16);
        o.y = (uint)f2bf(a.z) | ((uint)f2bf(a.w) << 16);
        o.z = (uint)f2bf(b.x) | ((uint)f2bf(b.y) << 16);
        o.w = (uint)f2bf(b.z) | ((uint)f2bf(b.w) << 16);
        *(uint4*)(Xb + (size_t)i * 8) = o;
    }
}

// ---------------- W[128][128] fp32 -> Wt[n][k] bf16 (transpose+cast) ----------
__global__ __launch_bounds__(256) void k_wt(const float* __restrict__ W,
                                            ushort* __restrict__ Wt) {
    int t = threadIdx.x;
    for (int i = t; i < FDIM * FDIM; i += 256) {
        int k = i >> 7, n = i & 127;
        Wt[n * FDIM + k] = f2bf(W[i]);
    }
}

// ---------------- bf16 MFMA GEMM: H[N,128] = X[N,128] @ Wt^T ----------------
// 256 thr = 4 waves; wave computes 16 rows x 128 cols via mfma_f32_16x16x32_bf16.
// A and B frags use identical per-lane k-mapping -> k-permutation cancels.
__global__ __launch_bounds__(256) void k_gemm(const ushort* __restrict__ X,
                                              const ushort* __restrict__ Wt,
                                              ushort* __restrict__ H, int N) {
    int t = threadIdx.x;
    int wave = t >> 6, l = t & 63;
    int m = l & 15, kg = (l >> 4) * 8;
    int r0 = blockIdx.x * 64 + wave * 16;
    int row = r0 + m;
    short8v a[4];
    if (row < N) {
#pragma unroll
        for (int ks = 0; ks < 4; ks++)
            a[ks] = *(const short8v*)(X + (size_t)row * FDIM + ks * 32 + kg);
    } else {
#pragma unroll
        for (int ks = 0; ks < 4; ks++) a[ks] = (short8v)0;
    }
    int orow = r0 + (l >> 4) * 4;
#pragma unroll
    for (int c = 0; c < 8; c++) {
        f32x4 acc = {0.f, 0.f, 0.f, 0.f};
#pragma unroll
        for (int ks = 0; ks < 4; ks++) {
            short8v b = *(const short8v*)(Wt + (size_t)(c * 16 + m) * FDIM + ks * 32 + kg);
            acc = __builtin_amdgcn_mfma_f32_16x16x32_bf16(a[ks], b, acc, 0, 0, 0);
        }
#pragma unroll
        for (int j = 0; j < 4; j++)
            if (orow + j < N) H[(size_t)(orow + j) * FDIM + c * 16 + m] = f2bf(acc[j]);
    }
}

// ---------------- gather aggregation v3 (bf16 H) ----------------
// 1 node per wave iteration; 4 edge-slots in parallel (lane group eg = l>>4),
// 16 lanes x 8 bf16 features each; butterfly shfl_xor reduce over edge-slots.
template <int RELU, int POOL>
__global__ __launch_bounds__(256) void k_agg(const ushort* __restrict__ H,
                                             const int* __restrict__ rowptr,
                                             const int* __restrict__ csr_src,
                                             const float* __restrict__ csr_nrm,
                                             const float* __restrict__ dinv,
                                             const float* __restrict__ bias,
                                             ushort* __restrict__ Z,
                                             const int* __restrict__ batch,
                                             float* psum, int* gcnt, int NN) {
    __shared__ float pool[FDIM];
    __shared__ int pcnt;
    int t = threadIdx.x;
    int wave = t >> 6, l = t & 63;
    int eg = l >> 4, li = l & 15;
    int f0 = li * 8;
    int gmin = 0;
    if (POOL) {
        if (t < FDIM) pool[t] = 0.0f;
        if (t == 0) pcnt = 0;
        gmin = batch[blockIdx.x * 16];
        __syncthreads();
    }
    float bv[8];
#pragma unroll
    for (int j = 0; j < 8; j++) bv[j] = bias[f0 + j];

    for (int it = 0; it < 4; ++it) {
        int n = blockIdx.x * 16 + wave * 4 + it;
        if (n < NN) {
            float acc[8];
            if (eg == 0) {
                float di = dinv[n];
                float sw = di * di;
                uint4 hv = *(const uint4*)(H + (size_t)n * FDIM + f0);
                acc[0] = sw * bf2f_lo(hv.x); acc[1] = sw * bf2f_hi(hv.x);
                acc[2] = sw * bf2f_lo(hv.y); acc[3] = sw * bf2f_hi(hv.y);
                acc[4] = sw * bf2f_lo(hv.z); acc[5] = sw * bf2f_hi(hv.z);
                acc[6] = sw * bf2f_lo(hv.w); acc[7] = sw * bf2f_hi(hv.w);
            } else {
#pragma unroll
                for (int j = 0; j < 8; j++) acc[j] = 0.0f;
            }
            int rs = rowptr[n], re = rowptr[n + 1];
            for (int e = rs; e < re; e += 8) {
                int i0 = e + eg, i1 = e + 4 + eg;
                int c0 = min(i0, re - 1), c1 = min(i1, re - 1);
                int s0 = csr_src[c0], s1 = csr_src[c1];
                float w0 = (i0 < re) ? csr_nrm[c0] : 0.0f;
                float w1 = (i1 < re) ? csr_nrm[c1] : 0.0f;
                uint4 v0 = *(const uint4*)(H + (size_t)s0 * FDIM + f0);
                uint4 v1 = *(const uint4*)(H + (size_t)s1 * FDIM + f0);
                acc[0] = fmaf(w0, bf2f_lo(v0.x), acc[0]);
                acc[1] = fmaf(w0, bf2f_hi(v0.x), acc[1]);
                acc[2] = fmaf(w0, bf2f_lo(v0.y), acc[2]);
                acc[3] = fmaf(w0, bf2f_hi(v0.y), acc[3]);
                acc[4] = fmaf(w0, bf2f_lo(v0.z), acc[4]);
                acc[5] = fmaf(w0, bf2f_hi(v0.z), acc[5]);
                acc[6] = fmaf(w0, bf2f_lo(v0.w), acc[6]);
                acc[7] = fmaf(w0, bf2f_hi(v0.w), acc[7]);
                acc[0] = fmaf(w1, bf2f_lo(v1.x), acc[0]);
                acc[1] = fmaf(w1, bf2f_hi(v1.x), acc[1]);
                acc[2] = fmaf(w1, bf2f_lo(v1.y), acc[2]);
                acc[3] = fmaf(w1, bf2f_hi(v1.y), acc[3]);
                acc[4] = fmaf(w1, bf2f_lo(v1.z), acc[4]);
                acc[5] = fmaf(w1, bf2f_hi(v1.z), acc[5]);
                acc[6] = fmaf(w1, bf2f_lo(v1.w), acc[6]);
                acc[7] = fmaf(w1, bf2f_hi(v1.w), acc[7]);
            }
#pragma unroll
            for (int j = 0; j < 8; j++) {
                acc[j] += __shfl_xor(acc[j], 16);
                acc[j] += __shfl_xor(acc[j], 32);
            }
            if (eg == 0) {
#pragma unroll
                for (int j = 0; j < 8; j++) acc[j] += bv[j];
                if (RELU) {
#pragma unroll
                    for (int j = 0; j < 8; j++) acc[j] = fmaxf(acc[j], 0.0f);
                }
                if (POOL) {
                    int g = batch[n];
                    if (g == gmin) {
#pragma unroll
                        for (int j = 0; j < 8; j++) atomicAdd(&pool[f0 + j], acc[j]);
                        if (li == 0) atomicAdd(&pcnt, 1);
                    } else {
#pragma unroll
                        for (int j = 0; j < 8; j++) atomicAdd(&psum[g * FDIM + f0 + j], acc[j]);
                        if (li == 0) atomicAdd(&gcnt[g], 1);
                    }
                } else {
                    uint4 o;
                    o.x = (uint)f2bf(acc[0]) | ((uint)f2bf(acc[1]) << 16);
                    o.y = (uint)f2bf(acc[2]) | ((uint)f2bf(acc[3]) << 16);
                    o.z = (uint)f2bf(acc[4]) | ((uint)f2bf(acc[5]) << 16);
                    o.w = (uint)f2bf(acc[6]) | ((uint)f2bf(acc[7]) << 16);
                    *(uint4*)(Z + (size_t)n * FDIM + f0) = o;
                }
            }
        }
    }
    if (POOL) {
        __syncthreads();
        if (t < FDIM) atomicAdd(&psum[gmin * FDIM + t], pool[t]);
        if (t == 0) atomicAdd(&gcnt[gmin], pcnt);
    }
}

// ---------------- mean + final FC: out[g] = (psum[g]/cnt) @ Wfc + bfc ---------
__global__ __launch_bounds__(128) void k_fc(const float* __restrict__ psum,
                                            const int* __restrict__ gcnt,
                                            const float* __restrict__ Wfc,
                                            const float* __restrict__ bfc,
                                            float* __restrict__ out) {
    __shared__ float p[FDIM];
    int g = blockIdx.x, f = threadIdx.x;
    float c = (float)max(gcnt[g], 1);
    p[f] = psum[g * FDIM + f] / c;
    __syncthreads();
    float acc = bfc[f];
#pragma unroll 8
    for (int k = 0; k < FDIM; k++) acc = fmaf(p[k], Wfc[k * FDIM + f], acc);
    out[g * FDIM + f] = acc;
}

extern "C" void kernel_launch(void* const* d_in, const int* in_sizes, int n_in,
                              void* d_out, int out_size, void* d_ws, size_t ws_size,
                              hipStream_t stream) {
    const float* x    = (const float*)d_in[0];
    const int*   ei   = (const int*)d_in[1];
    const float* ew   = (const float*)d_in[2];
    const int*   batch= (const int*)d_in[3];
    const float* W1   = (const float*)d_in[4];
    const float* b1   = (const float*)d_in[5];
    const float* W2   = (const float*)d_in[6];
    const float* b2   = (const float*)d_in[7];
    const float* Wfc  = (const float*)d_in[8];
    const float* bfc  = (const float*)d_in[9];
    float* out = (float*)d_out;

    int E  = in_sizes[2];       // 1,600,000
    int NN = in_sizes[3];       // 100,000
    int G  = out_size / FDIM;   // 64

    const int* src = ei;
    const int* dst = ei + E;

    char* ws = (char*)d_ws;
    size_t off = 0;
    auto alloc = [&](size_t bytes) -> void* {
        void* p = ws + off;
        off = (off + bytes + 255) & ~(size_t)255;
        return p;
    };
    float* deg     = (float*)alloc((size_t)NN * 4);       // becomes dinv in-place
    int*   cnt     = (int*)alloc((size_t)NN * 4);
    int*   rowptr  = (int*)alloc((size_t)(NN + 1) * 4);
    int*   fillpos = (int*)alloc((size_t)NN * 4);
    int*   bsum    = (int*)alloc(256 * 4);
    int*   boff    = (int*)alloc(256 * 4);
    int*   csr_src = (int*)alloc((size_t)E * 4);
    float* csr_nrm = (float*)alloc((size_t)E * 4);
    float* psum    = (float*)alloc((size_t)G * FDIM * 4);
    int*   gcnt    = (int*)alloc((size_t)G * 4);
    ushort* Xb     = (ushort*)alloc((size_t)NN * FDIM * 2);
    ushort* Bh     = (ushort*)alloc((size_t)NN * FDIM * 2);
    ushort* Bz     = (ushort*)alloc((size_t)NN * FDIM * 2);
    ushort* Wt1    = (ushort*)alloc((size_t)FDIM * FDIM * 2);
    ushort* Wt2    = (ushort*)alloc((size_t)FDIM * FDIM * 2);
    (void)ws_size; (void)n_in;

    int nbN = (NN + 255) / 256;
    int nbE = (E + 255) / 256;
    int NB  = (NN + 1023) / 1024;   // 98
    int nb8 = (NN * FDIM / 8 + 255) / 256;

    k_init<<<nbN, 256, 0, stream>>>(deg, cnt, psum, gcnt, NN, G * FDIM, G);
    k_degcnt<<<nbE, 256, 0, stream>>>(dst, ew, deg, cnt, E);
    k_dinv<<<nbN, 256, 0, stream>>>(deg, NN);
    k_bsum<<<NB, 256, 0, stream>>>(cnt, bsum, NN);
    k_btops<<<1, 256, 0, stream>>>(bsum, boff, rowptr, NB, NN);
    k_scan<<<NB, 256, 0, stream>>>(cnt, boff, rowptr, fillpos, NN);
    k_fill<<<nbE, 256, 0, stream>>>(src, dst, ew, deg, fillpos, csr_src, csr_nrm, E);
    k_castx<<<nb8, 256, 0, stream>>>(x, Xb, NN * FDIM / 8);
    k_wt<<<1, 256, 0, stream>>>(W1, Wt1);
    k_wt<<<1, 256, 0, stream>>>(W2, Wt2);

    int nbG = (NN + 63) / 64;
    int nbA = (NN + 15) / 16;
    // layer 1: h1 = x@W1 ; z1 = relu(Agg(h1)+b1)
    k_gemm<<<nbG, 256, 0, stream>>>(Xb, Wt1, Bh, NN);
    k_agg<1, 0><<<nbA, 256, 0, stream>>>(Bh, rowptr, csr_src, csr_nrm, deg, b1,
                                         Bz, batch, psum, gcnt, NN);
    // layer 2: h2 = z1@W2 ; z2 = Agg(h2)+b2, fused mean-pool accumulation
    k_gemm<<<nbG, 256, 0, stream>>>(Bz, Wt2, Bh, NN);
    k_agg<0, 1><<<nbA, 256, 0, stream>>>(Bh, rowptr, csr_src, csr_nrm, deg, b2,
                                         nullptr, batch, psum, gcnt, NN);
    // out = (psum/cnt) @ Wfc + bfc
    k_fc<<<G, 128, 0, stream>>>(psum, gcnt, Wfc, bfc, out);
}

// Round 4
// 440.057 us; speedup vs baseline: 3.3601x; 1.2133x over previous
//
#include <hip/hip_runtime.h>

// GCN: z1 = relu(Agg(x@W1)+b1); z2 = Agg(z1@W2)+b2; out = meanpool(z2)@Wfc + bfc
// Agg(h)[d] = dinv[d]^2 * h[d] + sum_{e: s->d} dinv[s]*w[e]*dinv[d] * h[s]
// Intermediates bf16, accumulation fp32, MFMA GEMMs.
// CSR build: 8-way privatized packed-u64 histograms (cnt|fixpt(ew-sum)),
// group-privatized fill atomics, interleaved uint2 {src, nrm} payload.

constexpr int FDIM = 128;

typedef __attribute__((ext_vector_type(8))) short short8v;
typedef __attribute__((ext_vector_type(4))) float f32x4;

__device__ __forceinline__ ushort f2bf(float f) {
    uint u = __float_as_uint(f);
    return (ushort)((u + 0x7fffu + ((u >> 16) & 1u)) >> 16);
}
__device__ __forceinline__ float bf2f_lo(uint d) { return __uint_as_float(d << 16); }
__device__ __forceinline__ float bf2f_hi(uint d) { return __uint_as_float(d & 0xffff0000u); }

// ---------------- init: zero privatized histograms + pool accumulators -------
__global__ __launch_bounds__(256) void k_init(unsigned long long* packed, float* psum,
                                              int* gcnt, int NN, int PS, int G) {
    int i = blockIdx.x * 256 + threadIdx.x;
    if (i < NN) {
#pragma unroll
        for (int g = 0; g < 8; g++) packed[(size_t)g * NN + i] = 0ULL;
    }
    if (i < PS) psum[i] = 0.0f;
    if (i < G) gcnt[i] = 0;
}

// ---------------- privatized degree+count histogram (1 packed atomic/edge) ---
__global__ __launch_bounds__(256) void k_hist8(const int* __restrict__ dst,
                                               const float* __restrict__ ew,
                                               unsigned long long* __restrict__ packed,
                                               int E, int NN) {
    int e = blockIdx.x * 256 + threadIdx.x;
    if (e < E) {
        int d = dst[e];
        uint fix = __float2uint_rn(ew[e] * 16777216.0f);   // 2^24 fixed point
        unsigned long long v = (1ULL << 32) | (unsigned long long)fix;
        atomicAdd(&packed[(size_t)(blockIdx.x & 7) * NN + d], v);
    }
}

// ---------------- merge 8 copies -> cnt, dinv, per-group prefix goff ---------
__global__ __launch_bounds__(256) void k_merge(const unsigned long long* __restrict__ packed,
                                               int* __restrict__ cnt,
                                               float* __restrict__ dinv,
                                               int* __restrict__ goff, int NN) {
    int n = blockIdx.x * 256 + threadIdx.x;
    if (n >= NN) return;
    int c = 0;
    unsigned long long lo = 0;
    int pre[8];
#pragma unroll
    for (int g = 0; g < 8; g++) {
        unsigned long long v = packed[(size_t)g * NN + n];
        pre[g] = c;
        c += (int)(v >> 32);
        lo += (v & 0xffffffffULL);
    }
    cnt[n] = c;
    float deg = 1.0f + (float)lo * 5.9604644775390625e-8f;  // 2^-24
    dinv[n] = rsqrtf(deg);
#pragma unroll
    for (int g = 0; g < 8; g++) goff[(size_t)g * NN + n] = pre[g];
}

// ---------------- exclusive scan of cnt -> rowptr (3-kernel, chunk=1024) -----
__global__ __launch_bounds__(256) void k_bsum(const int* __restrict__ cnt, int* bsum, int NN) {
    __shared__ int lds[256];
    int b = blockIdx.x, t = threadIdx.x;
    int base = b * 1024;
    int s = 0;
#pragma unroll
    for (int j = 0; j < 4; j++) {
        int i = base + j * 256 + t;
        if (i < NN) s += cnt[i];
    }
    lds[t] = s;
    __syncthreads();
    for (int off = 128; off > 0; off >>= 1) {
        if (t < off) lds[t] += lds[t + off];
        __syncthreads();
    }
    if (t == 0) bsum[b] = lds[0];
}

__global__ __launch_bounds__(256) void k_btops(const int* bsum, int* boff, int* rowptr,
                                               int NB, int NN) {
    __shared__ int lds[256];
    int t = threadIdx.x;
    if (t < NB) lds[t] = bsum[t];
    __syncthreads();
    if (t == 0) {
        int run = 0;
        for (int i = 0; i < NB; i++) { int v = lds[i]; boff[i] = run; run += v; }
        rowptr[NN] = run;   // == E
    }
}

__global__ __launch_bounds__(256) void k_scan(const int* __restrict__ cnt,
                                              const int* __restrict__ boff,
                                              int* rowptr, int NN) {
    __shared__ int lds[2][256];
    int b = blockIdx.x, t = threadIdx.x;
    int base = b * 1024 + t * 4;
    int v[4]; int s = 0;
#pragma unroll
    for (int j = 0; j < 4; j++) { v[j] = (base + j < NN) ? cnt[base + j] : 0; s += v[j]; }
    lds[0][t] = s;
    __syncthreads();
    int cur = 0;
    for (int off = 1; off < 256; off <<= 1) {
        int val = lds[cur][t];
        if (t >= off) val += lds[cur][t - off];
        lds[cur ^ 1][t] = val;
        __syncthreads();
        cur ^= 1;
    }
    int excl = lds[cur][t] - s + boff[b];
#pragma unroll
    for (int j = 0; j < 4; j++) {
        if (base + j < NN) rowptr[base + j] = excl;
        excl += v[j];
    }
}

// ---------------- CSR fill: group-privatized position atomics ----------------
__global__ __launch_bounds__(256) void k_fill(const int* __restrict__ src,
                                              const int* __restrict__ dst,
                                              const float* __restrict__ ew,
                                              const float* __restrict__ dinv,
                                              const int* __restrict__ rowptr,
                                              int* __restrict__ goff,
                                              uint2* __restrict__ csr, int E, int NN) {
    int e = blockIdx.x * 256 + threadIdx.x;
    if (e < E) {
        int d = dst[e], s = src[e];
        int rel = atomicAdd(&goff[(size_t)(blockIdx.x & 7) * NN + d], 1);
        int pos = rowptr[d] + rel;
        float nrm = dinv[s] * ew[e] * dinv[d];
        csr[pos] = make_uint2((uint)s, __float_as_uint(nrm));
    }
}

// ---------------- W[128][128] fp32 -> Wt[n][k] bf16 (transpose+cast) ---------
__global__ __launch_bounds__(256) void k_wt(const float* __restrict__ W,
                                            ushort* __restrict__ Wt) {
    int t = threadIdx.x;
    for (int i = t; i < FDIM * FDIM; i += 256) {
        int k = i >> 7, n = i & 127;
        Wt[n * FDIM + k] = f2bf(W[i]);
    }
}

// ---------------- bf16 MFMA GEMM: H[N,128] = X[N,128] @ Wt^T -----------------
// 256 thr = 4 waves; wave computes 16 rows x 128 cols via mfma_f32_16x16x32_bf16.
// TIN=float: converts fp32 rows to bf16 fragments in-register (layer 1).
template <typename TIN>
__global__ __launch_bounds__(256) void k_gemm(const TIN* __restrict__ X,
                                              const ushort* __restrict__ Wt,
                                              ushort* __restrict__ H, int N) {
    int t = threadIdx.x;
    int wave = t >> 6, l = t & 63;
    int m = l & 15, kg = (l >> 4) * 8;
    int r0 = blockIdx.x * 64 + wave * 16;
    int row = r0 + m;
    short8v a[4];
    if (row < N) {
#pragma unroll
        for (int ks = 0; ks < 4; ks++) {
            if constexpr (sizeof(TIN) == 2) {
                a[ks] = *(const short8v*)(X + (size_t)row * FDIM + ks * 32 + kg);
            } else {
                const float* xp = (const float*)X + (size_t)row * FDIM + ks * 32 + kg;
                float4 f0 = *(const float4*)xp;
                float4 f1 = *(const float4*)(xp + 4);
                short8v av;
                av[0] = (short)f2bf(f0.x); av[1] = (short)f2bf(f0.y);
                av[2] = (short)f2bf(f0.z); av[3] = (short)f2bf(f0.w);
                av[4] = (short)f2bf(f1.x); av[5] = (short)f2bf(f1.y);
                av[6] = (short)f2bf(f1.z); av[7] = (short)f2bf(f1.w);
                a[ks] = av;
            }
        }
    } else {
#pragma unroll
        for (int ks = 0; ks < 4; ks++) a[ks] = (short8v)0;
    }
    int orow = r0 + (l >> 4) * 4;
#pragma unroll
    for (int c = 0; c < 8; c++) {
        f32x4 acc = {0.f, 0.f, 0.f, 0.f};
#pragma unroll
        for (int ks = 0; ks < 4; ks++) {
            short8v b = *(const short8v*)(Wt + (size_t)(c * 16 + m) * FDIM + ks * 32 + kg);
            acc = __builtin_amdgcn_mfma_f32_16x16x32_bf16(a[ks], b, acc, 0, 0, 0);
        }
#pragma unroll
        for (int j = 0; j < 4; j++)
            if (orow + j < N) H[(size_t)(orow + j) * FDIM + c * 16 + m] = f2bf(acc[j]);
    }
}

// ---------------- gather aggregation (bf16 H, uint2 csr) ---------------------
// 1 node per wave iteration; 4 edge-slots (lane group eg = l>>4), 16 lanes x
// 8 bf16 features; butterfly shfl_xor reduce over edge-slots.
template <int RELU, int POOL>
__global__ __launch_bounds__(256) void k_agg(const ushort* __restrict__ H,
                                             const int* __restrict__ rowptr,
                                             const uint2* __restrict__ csr,
                                             const float* __restrict__ dinv,
                                             const float* __restrict__ bias,
                                             ushort* __restrict__ Z,
                                             const int* __restrict__ batch,
                                             float* psum, int* gcnt, int NN) {
    __shared__ float pool[FDIM];
    __shared__ int pcnt;
    int t = threadIdx.x;
    int wave = t >> 6, l = t & 63;
    int eg = l >> 4, li = l & 15;
    int f0 = li * 8;
    int gmin = 0;
    if (POOL) {
        if (t < FDIM) pool[t] = 0.0f;
        if (t == 0) pcnt = 0;
        gmin = batch[blockIdx.x * 16];
        __syncthreads();
    }
    float bv[8];
#pragma unroll
    for (int j = 0; j < 8; j++) bv[j] = bias[f0 + j];

    for (int it = 0; it < 4; ++it) {
        int n = blockIdx.x * 16 + wave * 4 + it;
        if (n < NN) {
            float acc[8];
            if (eg == 0) {
                float di = dinv[n];
                float sw = di * di;
                uint4 hv = *(const uint4*)(H + (size_t)n * FDIM + f0);
                acc[0] = sw * bf2f_lo(hv.x); acc[1] = sw * bf2f_hi(hv.x);
                acc[2] = sw * bf2f_lo(hv.y); acc[3] = sw * bf2f_hi(hv.y);
                acc[4] = sw * bf2f_lo(hv.z); acc[5] = sw * bf2f_hi(hv.z);
                acc[6] = sw * bf2f_lo(hv.w); acc[7] = sw * bf2f_hi(hv.w);
            } else {
#pragma unroll
                for (int j = 0; j < 8; j++) acc[j] = 0.0f;
            }
            int rs = rowptr[n], re = rowptr[n + 1];
            for (int e = rs; e < re; e += 8) {
                int i0 = e + eg, i1 = e + 4 + eg;
                int c0 = min(i0, re - 1), c1 = min(i1, re - 1);
                uint2 p0 = csr[c0], p1 = csr[c1];
                int s0 = (int)p0.x, s1 = (int)p1.x;
                float w0 = (i0 < re) ? __uint_as_float(p0.y) : 0.0f;
                float w1 = (i1 < re) ? __uint_as_float(p1.y) : 0.0f;
                uint4 v0 = *(const uint4*)(H + (size_t)s0 * FDIM + f0);
                uint4 v1 = *(const uint4*)(H + (size_t)s1 * FDIM + f0);
                acc[0] = fmaf(w0, bf2f_lo(v0.x), acc[0]);
                acc[1] = fmaf(w0, bf2f_hi(v0.x), acc[1]);
                acc[2] = fmaf(w0, bf2f_lo(v0.y), acc[2]);
                acc[3] = fmaf(w0, bf2f_hi(v0.y), acc[3]);
                acc[4] = fmaf(w0, bf2f_lo(v0.z), acc[4]);
                acc[5] = fmaf(w0, bf2f_hi(v0.z), acc[5]);
                acc[6] = fmaf(w0, bf2f_lo(v0.w), acc[6]);
                acc[7] = fmaf(w0, bf2f_hi(v0.w), acc[7]);
                acc[0] = fmaf(w1, bf2f_lo(v1.x), acc[0]);
                acc[1] = fmaf(w1, bf2f_hi(v1.x), acc[1]);
                acc[2] = fmaf(w1, bf2f_lo(v1.y), acc[2]);
                acc[3] = fmaf(w1, bf2f_hi(v1.y), acc[3]);
                acc[4] = fmaf(w1, bf2f_lo(v1.z), acc[4]);
                acc[5] = fmaf(w1, bf2f_hi(v1.z), acc[5]);
                acc[6] = fmaf(w1, bf2f_lo(v1.w), acc[6]);
                acc[7] = fmaf(w1, bf2f_hi(v1.w), acc[7]);
            }
#pragma unroll
            for (int j = 0; j < 8; j++) {
                acc[j] += __shfl_xor(acc[j], 16);
                acc[j] += __shfl_xor(acc[j], 32);
            }
            if (eg == 0) {
#pragma unroll
                for (int j = 0; j < 8; j++) acc[j] += bv[j];
                if (RELU) {
#pragma unroll
                    for (int j = 0; j < 8; j++) acc[j] = fmaxf(acc[j], 0.0f);
                }
                if (POOL) {
                    int g = batch[n];
                    if (g == gmin) {
#pragma unroll
                        for (int j = 0; j < 8; j++) atomicAdd(&pool[f0 + j], acc[j]);
                        if (li == 0) atomicAdd(&pcnt, 1);
                    } else {
#pragma unroll
                        for (int j = 0; j < 8; j++) atomicAdd(&psum[g * FDIM + f0 + j], acc[j]);
                        if (li == 0) atomicAdd(&gcnt[g], 1);
                    }
                } else {
                    uint4 o;
                    o.x = (uint)f2bf(acc[0]) | ((uint)f2bf(acc[1]) << 16);
                    o.y = (uint)f2bf(acc[2]) | ((uint)f2bf(acc[3]) << 16);
                    o.z = (uint)f2bf(acc[4]) | ((uint)f2bf(acc[5]) << 16);
                    o.w = (uint)f2bf(acc[6]) | ((uint)f2bf(acc[7]) << 16);
                    *(uint4*)(Z + (size_t)n * FDIM + f0) = o;
                }
            }
        }
    }
    if (POOL) {
        __syncthreads();
        if (t < FDIM) atomicAdd(&psum[gmin * FDIM + t], pool[t]);
        if (t == 0) atomicAdd(&gcnt[gmin], pcnt);
    }
}

// ---------------- mean + final FC: out[g] = (psum[g]/cnt) @ Wfc + bfc --------
__global__ __launch_bounds__(128) void k_fc(const float* __restrict__ psum,
                                            const int* __restrict__ gcnt,
                                            const float* __restrict__ Wfc,
                                            const float* __restrict__ bfc,
                                            float* __restrict__ out) {
    __shared__ float p[FDIM];
    int g = blockIdx.x, f = threadIdx.x;
    float c = (float)max(gcnt[g], 1);
    p[f] = psum[g * FDIM + f] / c;
    __syncthreads();
    float acc = bfc[f];
#pragma unroll 8
    for (int k = 0; k < FDIM; k++) acc = fmaf(p[k], Wfc[k * FDIM + f], acc);
    out[g * FDIM + f] = acc;
}

extern "C" void kernel_launch(void* const* d_in, const int* in_sizes, int n_in,
                              void* d_out, int out_size, void* d_ws, size_t ws_size,
                              hipStream_t stream) {
    const float* x    = (const float*)d_in[0];
    const int*   ei   = (const int*)d_in[1];
    const float* ew   = (const float*)d_in[2];
    const int*   batch= (const int*)d_in[3];
    const float* W1   = (const float*)d_in[4];
    const float* b1   = (const float*)d_in[5];
    const float* W2   = (const float*)d_in[6];
    const float* b2   = (const float*)d_in[7];
    const float* Wfc  = (const float*)d_in[8];
    const float* bfc  = (const float*)d_in[9];
    float* out = (float*)d_out;

    int E  = in_sizes[2];       // 1,600,000
    int NN = in_sizes[3];       // 100,000
    int G  = out_size / FDIM;   // 64

    const int* src = ei;
    const int* dst = ei + E;

    char* ws = (char*)d_ws;
    size_t off = 0;
    auto alloc = [&](size_t bytes) -> void* {
        void* p = ws + off;
        off = (off + bytes + 255) & ~(size_t)255;
        return p;
    };
    unsigned long long* packed = (unsigned long long*)alloc((size_t)NN * 8 * 8);
    int*   goff    = (int*)alloc((size_t)NN * 8 * 4);
    int*   cnt     = (int*)alloc((size_t)NN * 4);
    float* dinv    = (float*)alloc((size_t)NN * 4);
    int*   rowptr  = (int*)alloc((size_t)(NN + 1) * 4);
    int*   bsum    = (int*)alloc(256 * 4);
    int*   boff    = (int*)alloc(256 * 4);
    uint2* csr     = (uint2*)alloc((size_t)E * 8);
    float* psum    = (float*)alloc((size_t)G * FDIM * 4);
    int*   gcnt    = (int*)alloc((size_t)G * 4);
    ushort* Bh     = (ushort*)alloc((size_t)NN * FDIM * 2);
    ushort* Bz     = (ushort*)alloc((size_t)NN * FDIM * 2);
    ushort* Wt1    = (ushort*)alloc((size_t)FDIM * FDIM * 2);
    ushort* Wt2    = (ushort*)alloc((size_t)FDIM * FDIM * 2);
    (void)ws_size; (void)n_in;

    int nbN = (NN + 255) / 256;
    int nbE = (E + 255) / 256;
    int NB  = (NN + 1023) / 1024;   // 98

    k_init<<<nbN, 256, 0, stream>>>(packed, psum, gcnt, NN, G * FDIM, G);
    k_hist8<<<nbE, 256, 0, stream>>>(dst, ew, packed, E, NN);
    k_merge<<<nbN, 256, 0, stream>>>(packed, cnt, dinv, goff, NN);
    k_bsum<<<NB, 256, 0, stream>>>(cnt, bsum, NN);
    k_btops<<<1, 256, 0, stream>>>(bsum, boff, rowptr, NB, NN);
    k_scan<<<NB, 256, 0, stream>>>(cnt, boff, rowptr, NN);
    k_fill<<<nbE, 256, 0, stream>>>(src, dst, ew, dinv, rowptr, goff, csr, E, NN);
    k_wt<<<1, 256, 0, stream>>>(W1, Wt1);
    k_wt<<<1, 256, 0, stream>>>(W2, Wt2);

    int nbG = (NN + 63) / 64;
    int nbA = (NN + 15) / 16;
    // layer 1: h1 = x@W1 ; z1 = relu(Agg(h1)+b1)
    k_gemm<float><<<nbG, 256, 0, stream>>>(x, Wt1, Bh, NN);
    k_agg<1, 0><<<nbA, 256, 0, stream>>>(Bh, rowptr, csr, dinv, b1,
                                         Bz, batch, psum, gcnt, NN);
    // layer 2: h2 = z1@W2 ; z2 = Agg(h2)+b2, fused mean-pool accumulation
    k_gemm<ushort><<<nbG, 256, 0, stream>>>(Bz, Wt2, Bh, NN);
    k_agg<0, 1><<<nbA, 256, 0, stream>>>(Bh, rowptr, csr, dinv, b2,
                                         nullptr, batch, psum, gcnt, NN);
    // out = (psum/cnt) @ Wfc + bfc
    k_fc<<<G, 128, 0, stream>>>(psum, gcnt, Wfc, bfc, out);
}